// Round 18
// baseline (66.033 us; speedup 1.0000x reference)
//
#include <hip/hip_runtime.h>
#include <hip/hip_bf16.h>

#define DEV __device__ __forceinline__

typedef __attribute__((ext_vector_type(8))) short short8;
typedef __attribute__((ext_vector_type(4))) float f32x4;

constexpr int D   = 128;
constexpr int S   = 2048;
constexpr int Hh  = 4;
constexpr int DH  = 32;
// 1/sqrt(32) * log2(e): QK^T logits land directly in exp2 domain.
constexpr float QSCALE = 0.17677669529663687f * 1.4426950408889634f;
constexpr float EPSV = 1e-5f;

DEV unsigned short f2b(float f) {
  __hip_bfloat16 h = __float2bfloat16(f);
  return *reinterpret_cast<unsigned short*>(&h);
}
// HW packed f32->bf16 RNE conversion (T12 recipe; no builtin on gfx950).
DEV unsigned pack2(float a, float b) {
  unsigned r;
  asm("v_cvt_pk_bf16_f32 %0, %1, %2" : "=v"(r) : "v"(a), "v"(b));
  return r;
}

// exact-GELU via A&S 7.1.26 erf approximation (|eps| <= 1.5e-7).
DEV float fast_gelu(float v) {
  float z = v * 0.70710678118654752f;
  float a = fabsf(z);
  float t = __builtin_amdgcn_rcpf(1.0f + 0.3275911f * a);
  float p = t * (0.254829592f + t * (-0.284496736f +
            t * (1.421413741f + t * (-1.453152027f + t * 1.061405429f))));
  float e = __builtin_amdgcn_exp2f(-1.4426950408889634f * (z * z));
  float er = copysignf(1.0f - p * e, z);
  return 0.5f * v * (1.0f + er);
}

// Fragment-linear layout: a 16(row/col) x 32(k) MFMA operand tile is stored as
// [tile][k/32][lane=((k%32)/8)*16 + idx%16][k%8] -> every fragment load is
// base + lane*16B, one contiguous 1KB burst per wave.

// ---------------- prep: x -> xb (frag-linear), weights -> frag-linear ----------------
__global__ __launch_bounds__(256) void prep_kernel(
    const float* __restrict__ x,
    const float* __restrict__ Wq, const float* __restrict__ Wk,
    const float* __restrict__ Wv, const float* __restrict__ Wo,
    const float* __restrict__ W1, const float* __restrict__ W2,
    unsigned short* __restrict__ xb,
    unsigned short* __restrict__ wqT, unsigned short* __restrict__ wkT,
    unsigned short* __restrict__ wvT, unsigned short* __restrict__ woT,
    unsigned short* __restrict__ w1T, unsigned short* __restrict__ w2T) {
  int b = blockIdx.x, t = threadIdx.x;
  if (b < 1024) {
    int i8 = (b * 256 + t) * 8;
    int row = i8 >> 7, k0 = i8 & 127;
    const float4* p = reinterpret_cast<const float4*>(x + i8);
    float4 v0 = p[0], v1 = p[1];
    uint4 o;
    o.x = pack2(v0.x, v0.y);
    o.y = pack2(v0.z, v0.w);
    o.z = pack2(v1.x, v1.y);
    o.w = pack2(v1.z, v1.w);
    size_t off = ((size_t)(row >> 4) * 4 + (k0 >> 5)) * 512 + ((k0 & 31) >> 3) * 128 + (row & 15) * 8;
    *reinterpret_cast<uint4*>(xb + off) = o;
    return;
  }
  // all N are powers of two: divide -> shift/mask (no u32 divide)
  const float* src; unsigned short* dst; int nsh, KS, base;
  if      (b < 1088) { src = Wq; dst = wqT; nsh = 7; KS = 4;  base = 1024; }
  else if (b < 1152) { src = Wk; dst = wkT; nsh = 7; KS = 4;  base = 1088; }
  else if (b < 1216) { src = Wv; dst = wvT; nsh = 7; KS = 4;  base = 1152; }
  else if (b < 1280) { src = Wo; dst = woT; nsh = 7; KS = 4;  base = 1216; }
  else if (b < 1536) { src = W1; dst = w1T; nsh = 9; KS = 4;  base = 1280; }
  else               { src = W2; dst = w2T; nsh = 7; KS = 16; base = 1536; }
  int idx = (b - base) * 256 + t;
  int k = idx >> nsh, n = idx & ((1 << nsh) - 1);
  size_t off = ((size_t)(n >> 4) * KS + (k >> 5)) * 512 + ((k & 31) >> 3) * 128 + (n & 15) * 8 + (k & 7);
  dst[off] = f2b(src[idx]);
}

// ---------------- GEMM tile core, fragment-linear operands ----------------
template <int KDIM, bool SWAP>
DEV void gemm_tile_fl(const unsigned short* __restrict__ A,
                      const unsigned short* __restrict__ BT,
                      int tileA, int tileB0, int lane, f32x4 acc[8]) {
  constexpr int KS = KDIM / 32;
#pragma unroll
  for (int ks = 0; ks < KS; ++ks) {
    short8 a = *reinterpret_cast<const short8*>(A + ((size_t)(tileA * KS + ks) * 64 + lane) * 8);
#pragma unroll
    for (int c = 0; c < 8; ++c) {
      short8 b = *reinterpret_cast<const short8*>(BT + ((size_t)((tileB0 + c) * KS + ks) * 64 + lane) * 8);
      if constexpr (SWAP)
        acc[c] = __builtin_amdgcn_mfma_f32_16x16x32_bf16(b, a, acc[c], 0, 0, 0);
      else
        acc[c] = __builtin_amdgcn_mfma_f32_16x16x32_bf16(a, b, acc[c], 0, 0, 0);
    }
  }
}

// ---------------- QKV projection ----------------
__global__ __launch_bounds__(256) void qkv_kernel(
    const unsigned short* __restrict__ xb,
    const unsigned short* __restrict__ wqT, const unsigned short* __restrict__ wkT,
    const unsigned short* __restrict__ wvT,
    const float* __restrict__ bq, const float* __restrict__ bk, const float* __restrict__ bv,
    unsigned short* __restrict__ q, unsigned short* __restrict__ k,
    unsigned short* __restrict__ vT) {
  int w = threadIdx.x >> 6, lane = threadIdx.x & 63;
  int g = lane >> 4, ln = lane & 15;
  int z = blockIdx.y;
  int row0 = blockIdx.x * 64 + w * 16;
  int tileA = blockIdx.x * 4 + w;
  const unsigned short* BT = (z == 0) ? wqT : (z == 1) ? wkT : wvT;
  const float* bias = (z == 0) ? bq : (z == 1) ? bk : bv;
  f32x4 acc[8];
#pragma unroll
  for (int c = 0; c < 8; ++c) acc[c] = f32x4{0.f, 0.f, 0.f, 0.f};
  if (z == 2) {
    gemm_tile_fl<128, false>(xb, BT, tileA, 0, lane, acc);
    int t0 = row0 + 4 * g;
    int b_ = t0 >> 11, s0 = t0 & 2047;
#pragma unroll
    for (int c = 0; c < 8; ++c) {
      int n = c * 16 + ln;
      int h = n >> 5, dh = n & 31;
      float bi = bias[n];
      size_t tile = ((size_t)(b_ * Hh + h) * 32 + (s0 >> 6)) * 4 + ((s0 & 63) >> 5) * 2 + (dh >> 4);
      size_t off = tile * 512 + ((s0 & 31) >> 3) * 128 + (dh & 15) * 8 + (s0 & 7);
      uint2 st;
      st.x = pack2(acc[c][0] + bi, acc[c][1] + bi);
      st.y = pack2(acc[c][2] + bi, acc[c][3] + bi);
      *reinterpret_cast<uint2*>(vT + off) = st;
    }
  } else {
    gemm_tile_fl<128, true>(xb, BT, tileA, 0, lane, acc);
    unsigned short* dst = (z == 0) ? q : k;
    int t = row0 + ln;
    int b_ = t >> 11, s = t & 2047;
#pragma unroll
    for (int c = 0; c < 8; ++c) {
      int nc = c * 16 + 4 * g;
      int h = nc >> 5, dh0 = nc & 31;
      f32x4 bi = *reinterpret_cast<const f32x4*>(bias + nc);
      float f = 1.0f;
      if (z == 0) f = (dh0 < 8) ? -QSCALE : QSCALE;
      float v0 = (acc[c][0] + bi[0]) * f, v1 = (acc[c][1] + bi[1]) * f;
      float v2 = (acc[c][2] + bi[2]) * f, v3 = (acc[c][3] + bi[3]) * f;
      size_t tile = (size_t)(b_ * Hh + h) * 128 + (s >> 4);
      size_t off = tile * 512 + ((dh0 >> 3) * 16 + (s & 15)) * 8 + (dh0 & 7);
      uint2 st;
      st.x = pack2(v0, v1);
      st.y = pack2(v2, v3);
      *reinterpret_cast<uint2*>(dst + off) = st;
    }
  }
}

// ---------------- flash attention ----------------
// Round-17 softmax (guard-free exp2, ones-MFMA lsum, permlane P) +
// LDS-staged K/V DEDUP: the two w_q waves sharing a kv-quarter previously
// loaded identical K/V through L1 twice; per-CU L1 traffic (~2.6MB @64B/cyc)
// was the binding resource. Now w_q=0 stages K, w_q=1 stages V into a 32KB
// LDS buffer (reg-staging, 1KB-linear), both consume via LDS -> L1 bytes
// halve. 2 barriers/tile. Merge buffer overlays the staging area.
__global__ __launch_bounds__(512, 4) void attn_kernel(
    const unsigned short* __restrict__ q, const unsigned short* __restrict__ k,
    const unsigned short* __restrict__ vT, unsigned short* __restrict__ ao) {
  __shared__ float smem_f[8192];  // 32KB: K/V staging during loop, merge after
  unsigned short* kvbuf = reinterpret_cast<unsigned short*>(smem_f);
  int w = threadIdx.x >> 6, lane = threadIdx.x & 63;
  int g = lane >> 4, ln = lane & 15;
  int w_q = w >> 2, w_kv = w & 3;
  int lid = blockIdx.x;
  int c8 = lid & 7, j = lid >> 3;
  int bh = c8 + 8 * (j >> 5);   // bh-affine XCD swizzle: 4 bh per XCD
  int qt = j & 31;
  int qbase = qt * 64 + w_q * 32;
  const unsigned short* qp = q + (size_t)bh * S * DH + lane * 8;
  const unsigned short* kp = k + (size_t)bh * S * DH + lane * 8;
  const unsigned short* vp = vT + (size_t)bh * DH * S + lane * 8;
  unsigned short* kvq = kvbuf + w_kv * 4096;  // this quarter's 8KB slot

  short8 qfr[2];
#pragma unroll
  for (int qf = 0; qf < 2; ++qf)
    qfr[qf] = *reinterpret_cast<const short8*>(qp + (size_t)((qbase >> 4) + qf) * 512);

  short8 ones;
#pragma unroll
  for (int jj = 0; jj < 8; ++jj) ones[jj] = (short)0x3F80;  // bf16 1.0

  f32x4 acc[2][2];   // [vf][qf] O^T fragments (unnormalized)
  f32x4 acc_l[2];    // [qf] row-sum via ones-MFMA
#pragma unroll
  for (int a = 0; a < 2; ++a) {
    acc_l[a] = f32x4{0.f, 0.f, 0.f, 0.f};
#pragma unroll
    for (int b = 0; b < 2; ++b) acc[a][b] = f32x4{0.f, 0.f, 0.f, 0.f};
  }

  for (int kt = 0; kt < 8; ++kt) {
    int kv0 = w_kv * 512 + kt * 64;
    if (kt) __syncthreads();  // prior tile's LDS reads complete
    // stage this tile: w_q=0 -> K frags, w_q=1 -> V frags (each 4KB)
    if (w_q == 0) {
#pragma unroll
      for (int c = 0; c < 4; ++c) {
        short8 t = *reinterpret_cast<const short8*>(kp + (size_t)((kv0 >> 4) + c) * 512);
        *reinterpret_cast<short8*>(kvq + c * 512 + lane * 8) = t;
      }
    } else {
#pragma unroll
      for (int jf = 0; jf < 4; ++jf) {
        short8 t = *reinterpret_cast<const short8*>(vp + (size_t)((kv0 >> 6) * 4 + jf) * 512);
        *reinterpret_cast<short8*>(kvq + 2048 + jf * 512 + lane * 8) = t;
      }
    }
    __syncthreads();  // staged data visible
    short8 kf[4];
#pragma unroll
    for (int c = 0; c < 4; ++c)
      kf[c] = *reinterpret_cast<const short8*>(kvq + c * 512 + lane * 8);
    short8 vfr[2][2];
#pragma unroll
    for (int hv = 0; hv < 2; ++hv)
#pragma unroll
      for (int vf = 0; vf < 2; ++vf)
        vfr[hv][vf] = *reinterpret_cast<const short8*>(kvq + 2048 + (hv * 2 + vf) * 512 + lane * 8);
    f32x4 sst[4][2];
#pragma unroll
    for (int c = 0; c < 4; ++c)
#pragma unroll
      for (int qf = 0; qf < 2; ++qf)
        sst[c][qf] = __builtin_amdgcn_mfma_f32_16x16x32_bf16(kf[c], qfr[qf],
                                                             f32x4{0.f, 0.f, 0.f, 0.f}, 0, 0, 0);
    short8 pfr[2][2];
#pragma unroll
    for (int qf = 0; qf < 2; ++qf) {
#pragma unroll
      for (int c = 0; c < 4; ++c)
#pragma unroll
        for (int r = 0; r < 4; ++r)
          sst[c][qf][r] = __builtin_amdgcn_exp2f(sst[c][qf][r]);
      unsigned Wc[4][2];
#pragma unroll
      for (int c = 0; c < 4; ++c) {
        Wc[c][0] = pack2(sst[c][qf][0], sst[c][qf][1]);
        Wc[c][1] = pack2(sst[c][qf][2], sst[c][qf][3]);
      }
#pragma unroll
      for (int hv = 0; hv < 2; ++hv) {
        unsigned f00, f01, f10, f11;
        {
          auto st = __builtin_amdgcn_permlane32_swap(Wc[2 * hv][0], Wc[2 * hv + 1][0], false, false);
          auto uv = __builtin_amdgcn_permlane16_swap(st[0], st[1], false, false);
          f00 = uv[0]; f10 = uv[1];
        }
        {
          auto st = __builtin_amdgcn_permlane32_swap(Wc[2 * hv][1], Wc[2 * hv + 1][1], false, false);
          auto uv = __builtin_amdgcn_permlane16_swap(st[0], st[1], false, false);
          f01 = uv[0]; f11 = uv[1];
        }
        union { unsigned u[4]; short8 s8; } pu;
        pu.u[0] = f00; pu.u[1] = f01; pu.u[2] = f10; pu.u[3] = f11;
        pfr[qf][hv] = pu.s8;
      }
    }
    __builtin_amdgcn_s_setprio(1);
#pragma unroll
    for (int hv = 0; hv < 2; ++hv) {
#pragma unroll
      for (int qf = 0; qf < 2; ++qf) {
#pragma unroll
        for (int vf = 0; vf < 2; ++vf)
          acc[vf][qf] = __builtin_amdgcn_mfma_f32_16x16x32_bf16(vfr[hv][vf], pfr[qf][hv], acc[vf][qf], 0, 0, 0);
        acc_l[qf] = __builtin_amdgcn_mfma_f32_16x16x32_bf16(ones, pfr[qf][hv], acc_l[qf], 0, 0, 0);
      }
    }
    __builtin_amdgcn_s_setprio(0);
  }
  // ---- merge 4 kv-partials: plain sums (no max tracking) ----
  __syncthreads();
  if (w_kv) {
    float* mb = smem_f + ((w_q * 3 + (w_kv - 1)) * 64 + lane) * 20;
    mb[0] = acc_l[0][0]; mb[1] = acc_l[1][0];
#pragma unroll
    for (int vf = 0; vf < 2; ++vf)
#pragma unroll
      for (int qf = 0; qf < 2; ++qf)
#pragma unroll
        for (int r = 0; r < 4; ++r) mb[2 + (vf * 2 + qf) * 4 + r] = acc[vf][qf][r];
  }
  __syncthreads();
  if (w_kv == 0) {
    const float* mb0 = smem_f + ((w_q * 3 + 0) * 64 + lane) * 20;
    const float* mb1 = smem_f + ((w_q * 3 + 1) * 64 + lane) * 20;
    const float* mb2 = smem_f + ((w_q * 3 + 2) * 64 + lane) * 20;
    int b_ = bh >> 2, h = bh & 3;
#pragma unroll
    for (int qf = 0; qf < 2; ++qf) {
      float lt = acc_l[qf][0] + mb0[qf] + mb1[qf] + mb2[qf];
      float inv = 1.0f / lt;
      int qrow = qbase + qf * 16 + ln;
#pragma unroll
      for (int vf = 0; vf < 2; ++vf) {
        int kk = h * 32 + vf * 16 + 4 * g;
        int ai = 2 + (vf * 2 + qf) * 4;
        float o[4];
#pragma unroll
        for (int r = 0; r < 4; ++r)
          o[r] = (acc[vf][qf][r] + mb0[ai + r] + mb1[ai + r] + mb2[ai + r]) * inv;
        uint2 st;
        st.x = pack2(o[0], o[1]);
        st.y = pack2(o[2], o[3]);
        size_t grow = (size_t)b_ * S + qrow;
        size_t off = ((grow >> 4) * 4 + (kk >> 5)) * 512 + ((kk & 31) >> 3) * 128 + (grow & 15) * 8 + (kk & 7);
        *reinterpret_cast<uint2*>(ao + off) = st;
      }
    }
  }
}

// ---------------- fused tail: col-sliced waves, duplication-free weights ----------------
__global__ __launch_bounds__(512) void tail_kernel(
    const unsigned short* __restrict__ ao, const unsigned short* __restrict__ woT,
    const float* __restrict__ bo, const float* __restrict__ x,
    const float* __restrict__ g1t, const float* __restrict__ b1t,
    const float* __restrict__ g1s, const float* __restrict__ b1s,
    const unsigned short* __restrict__ w1T, const float* __restrict__ bf1,
    const unsigned short* __restrict__ w2T, const float* __restrict__ bf2,
    const float* __restrict__ g2t, const float* __restrict__ b2t,
    const float* __restrict__ g2s, const float* __restrict__ b2s,
    float* __restrict__ out) {
  __shared__ unsigned short xbl[32][136];   // x1 bf16, row stride 272B
  __shared__ unsigned short hl[32][520];    // h bf16, row stride 1040B
  __shared__ float stats[2][8][16][2];      // per-(rg,wn,ln) {sum, sumsq}
  int wn = threadIdx.x >> 6, lane = threadIdx.x & 63;
  int g = lane >> 4, ln = lane & 15;
  int nc = wn * 16 + 4 * g;                  // this wave's proj/ffn2 col base

  // ---- phase 1: out-proj (16 cols x both row-groups, full K=128) ----
  f32x4 acc1[2];
  acc1[0] = f32x4{0.f, 0.f, 0.f, 0.f};
  acc1[1] = f32x4{0.f, 0.f, 0.f, 0.f};
#pragma unroll
  for (int ks = 0; ks < 4; ++ks) {
    short8 b = *reinterpret_cast<const short8*>(woT + ((size_t)(wn * 4 + ks) * 64 + lane) * 8);
#pragma unroll
    for (int rg = 0; rg < 2; ++rg) {
      short8 a = *reinterpret_cast<const short8*>(ao + ((size_t)((blockIdx.x * 2 + rg) * 4 + ks) * 64 + lane) * 8);
      acc1[rg] = __builtin_amdgcn_mfma_f32_16x16x32_bf16(b, a, acc1[rg], 0, 0, 0);
    }
  }
  float rv[2][4];
  {
    f32x4 bi = *reinterpret_cast<const f32x4*>(bo + nc);
#pragma unroll
    for (int rg = 0; rg < 2; ++rg) {
      int row = blockIdx.x * 32 + rg * 16 + ln;
      f32x4 xr = *reinterpret_cast<const f32x4*>(x + (size_t)row * D + nc);
      float sum = 0.f, sq = 0.f;
#pragma unroll
      for (int r = 0; r < 4; ++r) {
        float v = acc1[rg][r] + bi[r] + xr[r];
        rv[rg][r] = v;
        sum += v; sq += v * v;
      }
      sum += __shfl_xor(sum, 16); sum += __shfl_xor(sum, 32);
      sq  += __shfl_xor(sq, 16);  sq  += __shfl_xor(sq, 32);
      stats[rg][wn][ln][0] = sum;
      stats[rg][wn][ln][1] = sq;
    }
  }
  __syncthreads();
  f32x4 xv[2];  // x1 (LN1 output), this wave's 16 cols, both rgs
  {
    f32x4 ga, bb;
    if (wn < 2) { ga = *reinterpret_cast<const f32x4*>(g1t + nc);
                  bb = *reinterpret_cast<const f32x4*>(b1t + nc); }
    else        { ga = *reinterpret_cast<const f32x4*>(g1s + nc - 32);
                  bb = *reinterpret_cast<const f32x4*>(b1s + nc - 32); }
#pragma unroll
    for (int rg = 0; rg < 2; ++rg) {
      float mu, rs;
      if (wn < 2) {
        float s  = stats[rg][0][ln][0] + stats[rg][1][ln][0];
        float q2 = stats[rg][0][ln][1] + stats[rg][1][ln][1];
        mu = s * (1.f / 32.f);
        rs = rsqrtf(q2 * (1.f / 32.f) - mu * mu + EPSV);
      } else {
        float s  = stats[rg][2][ln][0] + stats[rg][3][ln][0] + stats[rg][4][ln][0]
                 + stats[rg][5][ln][0] + stats[rg][6][ln][0] + stats[rg][7][ln][0];
        float q2 = stats[rg][2][ln][1] + stats[rg][3][ln][1] + stats[rg][4][ln][1]
                 + stats[rg][5][ln][1] + stats[rg][6][ln][1] + stats[rg][7][ln][1];
        mu = s * (1.f / 96.f);
        rs = rsqrtf(q2 * (1.f / 96.f) - mu * mu + EPSV);
      }
#pragma unroll
      for (int r = 0; r < 4; ++r)
        xv[rg][r] = (rv[rg][r] - mu) * rs * ga[r] + bb[r];
      uint2 sb;
      sb.x = pack2(xv[rg][0], xv[rg][1]);
      sb.y = pack2(xv[rg][2], xv[rg][3]);
      *reinterpret_cast<uint2*>(&xbl[rg * 16 + ln][nc]) = sb;
    }
  }
  __syncthreads();

  // ---- phase 2: ffn1 + exact GELU (64 h-cols x both rgs) ----
  {
    f32x4 acc2[2][4];
#pragma unroll
    for (int rg = 0; rg < 2; ++rg)
#pragma unroll
      for (int c = 0; c < 4; ++c) acc2[rg][c] = f32x4{0.f, 0.f, 0.f, 0.f};
#pragma unroll
    for (int ks = 0; ks < 4; ++ks) {
      short8 a0 = *reinterpret_cast<const short8*>(&xbl[ln][ks * 32 + 8 * g]);
      short8 a1 = *reinterpret_cast<const short8*>(&xbl[16 + ln][ks * 32 + 8 * g]);
#pragma unroll
      for (int c = 0; c < 4; ++c) {
        short8 b = *reinterpret_cast<const short8*>(w1T + ((size_t)((wn * 4 + c) * 4 + ks) * 64 + lane) * 8);
        acc2[0][c] = __builtin_amdgcn_mfma_f32_16x16x32_bf16(b, a0, acc2[0][c], 0, 0, 0);
        acc2[1][c] = __builtin_amdgcn_mfma_f32_16x16x32_bf16(b, a1, acc2[1][c], 0, 0, 0);
      }
    }
#pragma unroll
    for (int c = 0; c < 4; ++c) {
      int hc = wn * 64 + c * 16 + 4 * g;
      f32x4 bi = *reinterpret_cast<const f32x4*>(bf1 + hc);
#pragma unroll
      for (int rg = 0; rg < 2; ++rg) {
        float ge[4];
#pragma unroll
        for (int r = 0; r < 4; ++r)
          ge[r] = fast_gelu(acc2[rg][c][r] + bi[r]);
        uint2 stv;
        stv.x = pack2(ge[0], ge[1]);
        stv.y = pack2(ge[2], ge[3]);
        *reinterpret_cast<uint2*>(&hl[rg * 16 + ln][hc]) = stv;
      }
    }
  }
  __syncthreads();

  // ---- phase 3: ffn2 (16 out-cols x both rgs, full K=512) ----
  f32x4 acc3[2];
  acc3[0] = f32x4{0.f, 0.f, 0.f, 0.f};
  acc3[1] = f32x4{0.f, 0.f, 0.f, 0.f};
#pragma unroll
  for (int ks = 0; ks < 16; ++ks) {
    short8 b = *reinterpret_cast<const short8*>(w2T + ((size_t)(wn * 16 + ks) * 64 + lane) * 8);
    short8 a0 = *reinterpret_cast<const short8*>(&hl[ln][ks * 32 + 8 * g]);
    short8 a1 = *reinterpret_cast<const short8*>(&hl[16 + ln][ks * 32 + 8 * g]);
    acc3[0] = __builtin_amdgcn_mfma_f32_16x16x32_bf16(b, a0, acc3[0], 0, 0, 0);
    acc3[1] = __builtin_amdgcn_mfma_f32_16x16x32_bf16(b, a1, acc3[1], 0, 0, 0);
  }
  float rv2[2][4];
  {
    f32x4 bi = *reinterpret_cast<const f32x4*>(bf2 + nc);
#pragma unroll
    for (int rg = 0; rg < 2; ++rg) {
      float sum = 0.f, sq = 0.f;
#pragma unroll
      for (int r = 0; r < 4; ++r) {
        float v = acc3[rg][r] + bi[r] + xv[rg][r];
        rv2[rg][r] = v;
        sum += v; sq += v * v;
      }
      sum += __shfl_xor(sum, 16); sum += __shfl_xor(sum, 32);
      sq  += __shfl_xor(sq, 16);  sq  += __shfl_xor(sq, 32);
      stats[rg][wn][ln][0] = sum;
      stats[rg][wn][ln][1] = sq;
    }
  }
  __syncthreads();
  {
    f32x4 ga, bb;
    if (wn < 2) { ga = *reinterpret_cast<const f32x4*>(g2t + nc);
                  bb = *reinterpret_cast<const f32x4*>(b2t + nc); }
    else        { ga = *reinterpret_cast<const f32x4*>(g2s + nc - 32);
                  bb = *reinterpret_cast<const f32x4*>(b2s + nc - 32); }
#pragma unroll
    for (int rg = 0; rg < 2; ++rg) {
      float mu, rs;
      if (wn < 2) {
        float s  = stats[rg][0][ln][0] + stats[rg][1][ln][0];
        float q2 = stats[rg][0][ln][1] + stats[rg][1][ln][1];
        mu = s * (1.f / 32.f);
        rs = rsqrtf(q2 * (1.f / 32.f) - mu * mu + EPSV);
      } else {
        float s  = stats[rg][2][ln][0] + stats[rg][3][ln][0] + stats[rg][4][ln][0]
                 + stats[rg][5][ln][0] + stats[rg][6][ln][0] + stats[rg][7][ln][0];
        float q2 = stats[rg][2][ln][1] + stats[rg][3][ln][1] + stats[rg][4][ln][1]
                 + stats[rg][5][ln][1] + stats[rg][6][ln][1] + stats[rg][7][ln][1];
        mu = s * (1.f / 96.f);
        rs = rsqrtf(q2 * (1.f / 96.f) - mu * mu + EPSV);
      }
      int row = blockIdx.x * 32 + rg * 16 + ln;
      f32x4 o4;
#pragma unroll
      for (int r = 0; r < 4; ++r)
        o4[r] = (rv2[rg][r] - mu) * rs * ga[r] + bb[r];
      *reinterpret_cast<f32x4*>(out + (size_t)row * D + nc) = o4;
    }
  }
}

extern "C" void kernel_launch(void* const* d_in, const int* in_sizes, int n_in,
                              void* d_out, int out_size, void* d_ws, size_t ws_size,
                              hipStream_t stream) {
  (void)in_sizes; (void)n_in; (void)out_size; (void)ws_size;
  const float* x   = (const float*)d_in[0];
  const float* Wq  = (const float*)d_in[1];
  const float* bq  = (const float*)d_in[2];
  const float* Wk  = (const float*)d_in[3];
  const float* bk  = (const float*)d_in[4];
  const float* Wv  = (const float*)d_in[5];
  const float* bv  = (const float*)d_in[6];
  const float* Wo  = (const float*)d_in[7];
  const float* bo  = (const float*)d_in[8];
  const float* g1t = (const float*)d_in[9];
  const float* b1t = (const float*)d_in[10];
  const float* g1s = (const float*)d_in[11];
  const float* b1s = (const float*)d_in[12];
  const float* W1  = (const float*)d_in[13];
  const float* bf1 = (const float*)d_in[14];
  const float* W2  = (const float*)d_in[15];
  const float* bf2 = (const float*)d_in[16];
  const float* g2t = (const float*)d_in[17];
  const float* b2t = (const float*)d_in[18];
  const float* g2s = (const float*)d_in[19];
  const float* b2s = (const float*)d_in[20];

  char* ws = (char*)d_ws;
  unsigned short* xb  = (unsigned short*)(ws);                 // frag-linear x
  unsigned short* wqT = (unsigned short*)(ws + 4194304);
  unsigned short* wkT = wqT + 16384;
  unsigned short* wvT = wkT + 16384;
  unsigned short* woT = wvT + 16384;
  unsigned short* w1T = woT + 16384;   // frag-linear [32 tiles][4][64][8]
  unsigned short* w2T = w1T + 65536;   // frag-linear [8 tiles][16][64][8]
  unsigned short* qb  = w2T + 65536;   // fragment-linear Q
  unsigned short* kb  = qb + 2097152;  // fragment-linear K
  unsigned short* vT  = kb + 2097152;  // fragment-linear V
  unsigned short* ao  = vT + 2097152;  // fragment-linear attn output
  float* outp = (float*)d_out;

  prep_kernel<<<1792, 256, 0, stream>>>(x, Wq, Wk, Wv, Wo, W1, W2,
                                        xb, wqT, wkT, wvT, woT, w1T, w2T);
  qkv_kernel<<<dim3(256, 3), 256, 0, stream>>>(xb, wqT, wkT, wvT, bq, bk, bv, qb, kb, vT);
  attn_kernel<<<1024, 512, 0, stream>>>(qb, kb, vT, ao);
  tail_kernel<<<512, 512, 0, stream>>>(ao, woT, bo, x, g1t, b1t, g1s, b1s,
                                       w1T, bf1, w2T, bf2, g2t, b2t, g2s, b2s, outp);
}

// Round 19
// 60.661 us; speedup vs baseline: 1.0886x; 1.0886x over previous
//
#include <hip/hip_runtime.h>
#include <hip/hip_bf16.h>

#define DEV __device__ __forceinline__

typedef __attribute__((ext_vector_type(8))) short short8;
typedef __attribute__((ext_vector_type(4))) float f32x4;

constexpr int D   = 128;
constexpr int S   = 2048;
constexpr int Hh  = 4;
constexpr int DH  = 32;
// 1/sqrt(32) * log2(e): QK^T logits land directly in exp2 domain.
constexpr float QSCALE = 0.17677669529663687f * 1.4426950408889634f;
constexpr float EPSV = 1e-5f;

DEV unsigned short f2b(float f) {
  __hip_bfloat16 h = __float2bfloat16(f);
  return *reinterpret_cast<unsigned short*>(&h);
}
// HW packed f32->bf16 RNE conversion (T12 recipe; no builtin on gfx950).
DEV unsigned pack2(float a, float b) {
  unsigned r;
  asm("v_cvt_pk_bf16_f32 %0, %1, %2" : "=v"(r) : "v"(a), "v"(b));
  return r;
}

// exact-GELU via A&S 7.1.26 erf approximation (|eps| <= 1.5e-7).
DEV float fast_gelu(float v) {
  float z = v * 0.70710678118654752f;
  float a = fabsf(z);
  float t = __builtin_amdgcn_rcpf(1.0f + 0.3275911f * a);
  float p = t * (0.254829592f + t * (-0.284496736f +
            t * (1.421413741f + t * (-1.453152027f + t * 1.061405429f))));
  float e = __builtin_amdgcn_exp2f(-1.4426950408889634f * (z * z));
  float er = copysignf(1.0f - p * e, z);
  return 0.5f * v * (1.0f + er);
}

// Fragment-linear layout: a 16(row/col) x 32(k) MFMA operand tile is stored as
// [tile][k/32][lane=((k%32)/8)*16 + idx%16][k%8] -> every fragment load is
// base + lane*16B, one contiguous 1KB burst per wave.

// ---------------- prep: x -> xb (frag-linear), weights -> frag-linear ----------------
__global__ __launch_bounds__(256) void prep_kernel(
    const float* __restrict__ x,
    const float* __restrict__ Wq, const float* __restrict__ Wk,
    const float* __restrict__ Wv, const float* __restrict__ Wo,
    const float* __restrict__ W1, const float* __restrict__ W2,
    unsigned short* __restrict__ xb,
    unsigned short* __restrict__ wqT, unsigned short* __restrict__ wkT,
    unsigned short* __restrict__ wvT, unsigned short* __restrict__ woT,
    unsigned short* __restrict__ w1T, unsigned short* __restrict__ w2T) {
  int b = blockIdx.x, t = threadIdx.x;
  if (b < 1024) {
    int i8 = (b * 256 + t) * 8;
    int row = i8 >> 7, k0 = i8 & 127;
    const float4* p = reinterpret_cast<const float4*>(x + i8);
    float4 v0 = p[0], v1 = p[1];
    uint4 o;
    o.x = pack2(v0.x, v0.y);
    o.y = pack2(v0.z, v0.w);
    o.z = pack2(v1.x, v1.y);
    o.w = pack2(v1.z, v1.w);
    size_t off = ((size_t)(row >> 4) * 4 + (k0 >> 5)) * 512 + ((k0 & 31) >> 3) * 128 + (row & 15) * 8;
    *reinterpret_cast<uint4*>(xb + off) = o;
    return;
  }
  // all N are powers of two: divide -> shift/mask (no u32 divide)
  const float* src; unsigned short* dst; int nsh, KS, base;
  if      (b < 1088) { src = Wq; dst = wqT; nsh = 7; KS = 4;  base = 1024; }
  else if (b < 1152) { src = Wk; dst = wkT; nsh = 7; KS = 4;  base = 1088; }
  else if (b < 1216) { src = Wv; dst = wvT; nsh = 7; KS = 4;  base = 1152; }
  else if (b < 1280) { src = Wo; dst = woT; nsh = 7; KS = 4;  base = 1216; }
  else if (b < 1536) { src = W1; dst = w1T; nsh = 9; KS = 4;  base = 1280; }
  else               { src = W2; dst = w2T; nsh = 7; KS = 16; base = 1536; }
  int idx = (b - base) * 256 + t;
  int k = idx >> nsh, n = idx & ((1 << nsh) - 1);
  size_t off = ((size_t)(n >> 4) * KS + (k >> 5)) * 512 + ((k & 31) >> 3) * 128 + (n & 15) * 8 + (k & 7);
  dst[off] = f2b(src[idx]);
}

// ---------------- GEMM tile core, fragment-linear operands ----------------
template <int KDIM, bool SWAP>
DEV void gemm_tile_fl(const unsigned short* __restrict__ A,
                      const unsigned short* __restrict__ BT,
                      int tileA, int tileB0, int lane, f32x4 acc[8]) {
  constexpr int KS = KDIM / 32;
#pragma unroll
  for (int ks = 0; ks < KS; ++ks) {
    short8 a = *reinterpret_cast<const short8*>(A + ((size_t)(tileA * KS + ks) * 64 + lane) * 8);
#pragma unroll
    for (int c = 0; c < 8; ++c) {
      short8 b = *reinterpret_cast<const short8*>(BT + ((size_t)((tileB0 + c) * KS + ks) * 64 + lane) * 8);
      if constexpr (SWAP)
        acc[c] = __builtin_amdgcn_mfma_f32_16x16x32_bf16(b, a, acc[c], 0, 0, 0);
      else
        acc[c] = __builtin_amdgcn_mfma_f32_16x16x32_bf16(a, b, acc[c], 0, 0, 0);
    }
  }
}

// ---------------- QKV projection ----------------
__global__ __launch_bounds__(256) void qkv_kernel(
    const unsigned short* __restrict__ xb,
    const unsigned short* __restrict__ wqT, const unsigned short* __restrict__ wkT,
    const unsigned short* __restrict__ wvT,
    const float* __restrict__ bq, const float* __restrict__ bk, const float* __restrict__ bv,
    unsigned short* __restrict__ q, unsigned short* __restrict__ k,
    unsigned short* __restrict__ vT) {
  int w = threadIdx.x >> 6, lane = threadIdx.x & 63;
  int g = lane >> 4, ln = lane & 15;
  int z = blockIdx.y;
  int row0 = blockIdx.x * 64 + w * 16;
  int tileA = blockIdx.x * 4 + w;
  const unsigned short* BT = (z == 0) ? wqT : (z == 1) ? wkT : wvT;
  const float* bias = (z == 0) ? bq : (z == 1) ? bk : bv;
  f32x4 acc[8];
#pragma unroll
  for (int c = 0; c < 8; ++c) acc[c] = f32x4{0.f, 0.f, 0.f, 0.f};
  if (z == 2) {
    gemm_tile_fl<128, false>(xb, BT, tileA, 0, lane, acc);
    int t0 = row0 + 4 * g;
    int b_ = t0 >> 11, s0 = t0 & 2047;
#pragma unroll
    for (int c = 0; c < 8; ++c) {
      int n = c * 16 + ln;
      int h = n >> 5, dh = n & 31;
      float bi = bias[n];
      size_t tile = ((size_t)(b_ * Hh + h) * 32 + (s0 >> 6)) * 4 + ((s0 & 63) >> 5) * 2 + (dh >> 4);
      size_t off = tile * 512 + ((s0 & 31) >> 3) * 128 + (dh & 15) * 8 + (s0 & 7);
      uint2 st;
      st.x = pack2(acc[c][0] + bi, acc[c][1] + bi);
      st.y = pack2(acc[c][2] + bi, acc[c][3] + bi);
      *reinterpret_cast<uint2*>(vT + off) = st;
    }
  } else {
    gemm_tile_fl<128, true>(xb, BT, tileA, 0, lane, acc);
    unsigned short* dst = (z == 0) ? q : k;
    int t = row0 + ln;
    int b_ = t >> 11, s = t & 2047;
#pragma unroll
    for (int c = 0; c < 8; ++c) {
      int nc = c * 16 + 4 * g;
      int h = nc >> 5, dh0 = nc & 31;
      f32x4 bi = *reinterpret_cast<const f32x4*>(bias + nc);
      float f = 1.0f;
      if (z == 0) f = (dh0 < 8) ? -QSCALE : QSCALE;
      float v0 = (acc[c][0] + bi[0]) * f, v1 = (acc[c][1] + bi[1]) * f;
      float v2 = (acc[c][2] + bi[2]) * f, v3 = (acc[c][3] + bi[3]) * f;
      size_t tile = (size_t)(b_ * Hh + h) * 128 + (s >> 4);
      size_t off = tile * 512 + ((dh0 >> 3) * 16 + (s & 15)) * 8 + (dh0 & 7);
      uint2 st;
      st.x = pack2(v0, v1);
      st.y = pack2(v2, v3);
      *reinterpret_cast<uint2*>(dst + off) = st;
    }
  }
}

// ---------------- flash attention (round-17 best: guard-free softmax,
// bh-affine XCD swizzle, K software prefetch, barrier-free main loop) -------
__global__ __launch_bounds__(512, 4) void attn_kernel(
    const unsigned short* __restrict__ q, const unsigned short* __restrict__ k,
    const unsigned short* __restrict__ vT, unsigned short* __restrict__ ao) {
  __shared__ float smem_f[7680];  // merge buffer only (30720 B)
  int w = threadIdx.x >> 6, lane = threadIdx.x & 63;
  int g = lane >> 4, ln = lane & 15;
  int w_q = w >> 2, w_kv = w & 3;
  int lid = blockIdx.x;
  int c8 = lid & 7, j = lid >> 3;
  int bh = c8 + 8 * (j >> 5);   // bh-affine XCD swizzle: 4 bh per XCD
  int qt = j & 31;
  int qbase = qt * 64 + w_q * 32;
  const unsigned short* qp = q + (size_t)bh * S * DH + lane * 8;
  const unsigned short* kp = k + (size_t)bh * S * DH + lane * 8;
  const unsigned short* vp = vT + (size_t)bh * DH * S + lane * 8;

  short8 qfr[2];
#pragma unroll
  for (int qf = 0; qf < 2; ++qf)
    qfr[qf] = *reinterpret_cast<const short8*>(qp + (size_t)((qbase >> 4) + qf) * 512);

  short8 ones;
#pragma unroll
  for (int jj = 0; jj < 8; ++jj) ones[jj] = (short)0x3F80;  // bf16 1.0

  f32x4 acc[2][2];   // [vf][qf] O^T fragments (unnormalized)
  f32x4 acc_l[2];    // [qf] row-sum via ones-MFMA
#pragma unroll
  for (int a = 0; a < 2; ++a) {
    acc_l[a] = f32x4{0.f, 0.f, 0.f, 0.f};
#pragma unroll
    for (int b = 0; b < 2; ++b) acc[a][b] = f32x4{0.f, 0.f, 0.f, 0.f};
  }

  short8 kf[4];
  {
    int kv0 = w_kv * 512;
#pragma unroll
    for (int c = 0; c < 4; ++c)
      kf[c] = *reinterpret_cast<const short8*>(kp + (size_t)((kv0 >> 4) + c) * 512);
  }

#pragma unroll 2
  for (int kt = 0; kt < 8; ++kt) {
    int kv0 = w_kv * 512 + kt * 64;
    short8 vfr[2][2];
#pragma unroll
    for (int hv = 0; hv < 2; ++hv)
#pragma unroll
      for (int vf = 0; vf < 2; ++vf)
        vfr[hv][vf] = *reinterpret_cast<const short8*>(vp + (size_t)((kv0 >> 6) * 4 + hv * 2 + vf) * 512);
    short8 kf_n[4];
    {
      int ktn = (kt < 7) ? kt + 1 : 7;
      int kvn = w_kv * 512 + ktn * 64;
#pragma unroll
      for (int c = 0; c < 4; ++c)
        kf_n[c] = *reinterpret_cast<const short8*>(kp + (size_t)((kvn >> 4) + c) * 512);
    }
    f32x4 sst[4][2];
#pragma unroll
    for (int c = 0; c < 4; ++c)
#pragma unroll
      for (int qf = 0; qf < 2; ++qf)
        sst[c][qf] = __builtin_amdgcn_mfma_f32_16x16x32_bf16(kf[c], qfr[qf],
                                                             f32x4{0.f, 0.f, 0.f, 0.f}, 0, 0, 0);
    short8 pfr[2][2];
#pragma unroll
    for (int qf = 0; qf < 2; ++qf) {
#pragma unroll
      for (int c = 0; c < 4; ++c)
#pragma unroll
        for (int r = 0; r < 4; ++r)
          sst[c][qf][r] = __builtin_amdgcn_exp2f(sst[c][qf][r]);
      unsigned Wc[4][2];
#pragma unroll
      for (int c = 0; c < 4; ++c) {
        Wc[c][0] = pack2(sst[c][qf][0], sst[c][qf][1]);
        Wc[c][1] = pack2(sst[c][qf][2], sst[c][qf][3]);
      }
#pragma unroll
      for (int hv = 0; hv < 2; ++hv) {
        unsigned f00, f01, f10, f11;
        {
          auto st = __builtin_amdgcn_permlane32_swap(Wc[2 * hv][0], Wc[2 * hv + 1][0], false, false);
          auto uv = __builtin_amdgcn_permlane16_swap(st[0], st[1], false, false);
          f00 = uv[0]; f10 = uv[1];
        }
        {
          auto st = __builtin_amdgcn_permlane32_swap(Wc[2 * hv][1], Wc[2 * hv + 1][1], false, false);
          auto uv = __builtin_amdgcn_permlane16_swap(st[0], st[1], false, false);
          f01 = uv[0]; f11 = uv[1];
        }
        union { unsigned u[4]; short8 s8; } pu;
        pu.u[0] = f00; pu.u[1] = f01; pu.u[2] = f10; pu.u[3] = f11;
        pfr[qf][hv] = pu.s8;
      }
    }
    __builtin_amdgcn_s_setprio(1);
#pragma unroll
    for (int hv = 0; hv < 2; ++hv) {
#pragma unroll
      for (int qf = 0; qf < 2; ++qf) {
#pragma unroll
        for (int vf = 0; vf < 2; ++vf)
          acc[vf][qf] = __builtin_amdgcn_mfma_f32_16x16x32_bf16(vfr[hv][vf], pfr[qf][hv], acc[vf][qf], 0, 0, 0);
        acc_l[qf] = __builtin_amdgcn_mfma_f32_16x16x32_bf16(ones, pfr[qf][hv], acc_l[qf], 0, 0, 0);
      }
    }
    __builtin_amdgcn_s_setprio(0);
#pragma unroll
    for (int c = 0; c < 4; ++c) kf[c] = kf_n[c];
  }
  // ---- merge 4 kv-partials: plain sums (no max tracking) ----
  __syncthreads();
  if (w_kv) {
    float* mb = smem_f + ((w_q * 3 + (w_kv - 1)) * 64 + lane) * 20;
    mb[0] = acc_l[0][0]; mb[1] = acc_l[1][0];
#pragma unroll
    for (int vf = 0; vf < 2; ++vf)
#pragma unroll
      for (int qf = 0; qf < 2; ++qf)
#pragma unroll
        for (int r = 0; r < 4; ++r) mb[2 + (vf * 2 + qf) * 4 + r] = acc[vf][qf][r];
  }
  __syncthreads();
  if (w_kv == 0) {
    const float* mb0 = smem_f + ((w_q * 3 + 0) * 64 + lane) * 20;
    const float* mb1 = smem_f + ((w_q * 3 + 1) * 64 + lane) * 20;
    const float* mb2 = smem_f + ((w_q * 3 + 2) * 64 + lane) * 20;
    int b_ = bh >> 2, h = bh & 3;
#pragma unroll
    for (int qf = 0; qf < 2; ++qf) {
      float lt = acc_l[qf][0] + mb0[qf] + mb1[qf] + mb2[qf];
      float inv = 1.0f / lt;
      int qrow = qbase + qf * 16 + ln;
#pragma unroll
      for (int vf = 0; vf < 2; ++vf) {
        int kk = h * 32 + vf * 16 + 4 * g;
        int ai = 2 + (vf * 2 + qf) * 4;
        float o[4];
#pragma unroll
        for (int r = 0; r < 4; ++r)
          o[r] = (acc[vf][qf][r] + mb0[ai + r] + mb1[ai + r] + mb2[ai + r]) * inv;
        uint2 st;
        st.x = pack2(o[0], o[1]);
        st.y = pack2(o[2], o[3]);
        size_t grow = (size_t)b_ * S + qrow;
        size_t off = ((grow >> 4) * 4 + (kk >> 5)) * 512 + ((kk & 31) >> 3) * 128 + (grow & 15) * 8 + (kk & 7);
        *reinterpret_cast<uint2*>(ao + off) = st;
      }
    }
  }
}

// ---------------- fused tail: col-sliced waves, duplication-free weights ----------------
__global__ __launch_bounds__(512) void tail_kernel(
    const unsigned short* __restrict__ ao, const unsigned short* __restrict__ woT,
    const float* __restrict__ bo, const float* __restrict__ x,
    const float* __restrict__ g1t, const float* __restrict__ b1t,
    const float* __restrict__ g1s, const float* __restrict__ b1s,
    const unsigned short* __restrict__ w1T, const float* __restrict__ bf1,
    const unsigned short* __restrict__ w2T, const float* __restrict__ bf2,
    const float* __restrict__ g2t, const float* __restrict__ b2t,
    const float* __restrict__ g2s, const float* __restrict__ b2s,
    float* __restrict__ out) {
  __shared__ unsigned short xbl[32][136];   // x1 bf16, row stride 272B
  __shared__ unsigned short hl[32][520];    // h bf16, row stride 1040B
  __shared__ float stats[2][8][16][2];      // per-(rg,wn,ln) {sum, sumsq}
  int wn = threadIdx.x >> 6, lane = threadIdx.x & 63;
  int g = lane >> 4, ln = lane & 15;
  int nc = wn * 16 + 4 * g;                  // this wave's proj/ffn2 col base

  // ---- phase 1: out-proj (16 cols x both row-groups, full K=128) ----
  f32x4 acc1[2];
  acc1[0] = f32x4{0.f, 0.f, 0.f, 0.f};
  acc1[1] = f32x4{0.f, 0.f, 0.f, 0.f};
#pragma unroll
  for (int ks = 0; ks < 4; ++ks) {
    short8 b = *reinterpret_cast<const short8*>(woT + ((size_t)(wn * 4 + ks) * 64 + lane) * 8);
#pragma unroll
    for (int rg = 0; rg < 2; ++rg) {
      short8 a = *reinterpret_cast<const short8*>(ao + ((size_t)((blockIdx.x * 2 + rg) * 4 + ks) * 64 + lane) * 8);
      acc1[rg] = __builtin_amdgcn_mfma_f32_16x16x32_bf16(b, a, acc1[rg], 0, 0, 0);
    }
  }
  float rv[2][4];
  {
    f32x4 bi = *reinterpret_cast<const f32x4*>(bo + nc);
#pragma unroll
    for (int rg = 0; rg < 2; ++rg) {
      int row = blockIdx.x * 32 + rg * 16 + ln;
      f32x4 xr = *reinterpret_cast<const f32x4*>(x + (size_t)row * D + nc);
      float sum = 0.f, sq = 0.f;
#pragma unroll
      for (int r = 0; r < 4; ++r) {
        float v = acc1[rg][r] + bi[r] + xr[r];
        rv[rg][r] = v;
        sum += v; sq += v * v;
      }
      sum += __shfl_xor(sum, 16); sum += __shfl_xor(sum, 32);
      sq  += __shfl_xor(sq, 16);  sq  += __shfl_xor(sq, 32);
      stats[rg][wn][ln][0] = sum;
      stats[rg][wn][ln][1] = sq;
    }
  }
  __syncthreads();
  f32x4 xv[2];  // x1 (LN1 output), this wave's 16 cols, both rgs
  {
    f32x4 ga, bb;
    if (wn < 2) { ga = *reinterpret_cast<const f32x4*>(g1t + nc);
                  bb = *reinterpret_cast<const f32x4*>(b1t + nc); }
    else        { ga = *reinterpret_cast<const f32x4*>(g1s + nc - 32);
                  bb = *reinterpret_cast<const f32x4*>(b1s + nc - 32); }
#pragma unroll
    for (int rg = 0; rg < 2; ++rg) {
      float mu, rs;
      if (wn < 2) {
        float s  = stats[rg][0][ln][0] + stats[rg][1][ln][0];
        float q2 = stats[rg][0][ln][1] + stats[rg][1][ln][1];
        mu = s * (1.f / 32.f);
        rs = rsqrtf(q2 * (1.f / 32.f) - mu * mu + EPSV);
      } else {
        float s  = stats[rg][2][ln][0] + stats[rg][3][ln][0] + stats[rg][4][ln][0]
                 + stats[rg][5][ln][0] + stats[rg][6][ln][0] + stats[rg][7][ln][0];
        float q2 = stats[rg][2][ln][1] + stats[rg][3][ln][1] + stats[rg][4][ln][1]
                 + stats[rg][5][ln][1] + stats[rg][6][ln][1] + stats[rg][7][ln][1];
        mu = s * (1.f / 96.f);
        rs = rsqrtf(q2 * (1.f / 96.f) - mu * mu + EPSV);
      }
#pragma unroll
      for (int r = 0; r < 4; ++r)
        xv[rg][r] = (rv[rg][r] - mu) * rs * ga[r] + bb[r];
      uint2 sb;
      sb.x = pack2(xv[rg][0], xv[rg][1]);
      sb.y = pack2(xv[rg][2], xv[rg][3]);
      *reinterpret_cast<uint2*>(&xbl[rg * 16 + ln][nc]) = sb;
    }
  }
  __syncthreads();

  // ---- phase 2: ffn1 + exact GELU (64 h-cols x both rgs) ----
  {
    f32x4 acc2[2][4];
#pragma unroll
    for (int rg = 0; rg < 2; ++rg)
#pragma unroll
      for (int c = 0; c < 4; ++c) acc2[rg][c] = f32x4{0.f, 0.f, 0.f, 0.f};
#pragma unroll
    for (int ks = 0; ks < 4; ++ks) {
      short8 a0 = *reinterpret_cast<const short8*>(&xbl[ln][ks * 32 + 8 * g]);
      short8 a1 = *reinterpret_cast<const short8*>(&xbl[16 + ln][ks * 32 + 8 * g]);
#pragma unroll
      for (int c = 0; c < 4; ++c) {
        short8 b = *reinterpret_cast<const short8*>(w1T + ((size_t)((wn * 4 + c) * 4 + ks) * 64 + lane) * 8);
        acc2[0][c] = __builtin_amdgcn_mfma_f32_16x16x32_bf16(b, a0, acc2[0][c], 0, 0, 0);
        acc2[1][c] = __builtin_amdgcn_mfma_f32_16x16x32_bf16(b, a1, acc2[1][c], 0, 0, 0);
      }
    }
#pragma unroll
    for (int c = 0; c < 4; ++c) {
      int hc = wn * 64 + c * 16 + 4 * g;
      f32x4 bi = *reinterpret_cast<const f32x4*>(bf1 + hc);
#pragma unroll
      for (int rg = 0; rg < 2; ++rg) {
        float ge[4];
#pragma unroll
        for (int r = 0; r < 4; ++r)
          ge[r] = fast_gelu(acc2[rg][c][r] + bi[r]);
        uint2 stv;
        stv.x = pack2(ge[0], ge[1]);
        stv.y = pack2(ge[2], ge[3]);
        *reinterpret_cast<uint2*>(&hl[rg * 16 + ln][hc]) = stv;
      }
    }
  }
  __syncthreads();

  // ---- phase 3: ffn2 (16 out-cols x both rgs, full K=512) ----
  f32x4 acc3[2];
  acc3[0] = f32x4{0.f, 0.f, 0.f, 0.f};
  acc3[1] = f32x4{0.f, 0.f, 0.f, 0.f};
#pragma unroll
  for (int ks = 0; ks < 16; ++ks) {
    short8 b = *reinterpret_cast<const short8*>(w2T + ((size_t)(wn * 16 + ks) * 64 + lane) * 8);
    short8 a0 = *reinterpret_cast<const short8*>(&hl[ln][ks * 32 + 8 * g]);
    short8 a1 = *reinterpret_cast<const short8*>(&hl[16 + ln][ks * 32 + 8 * g]);
    acc3[0] = __builtin_amdgcn_mfma_f32_16x16x32_bf16(b, a0, acc3[0], 0, 0, 0);
    acc3[1] = __builtin_amdgcn_mfma_f32_16x16x32_bf16(b, a1, acc3[1], 0, 0, 0);
  }
  float rv2[2][4];
  {
    f32x4 bi = *reinterpret_cast<const f32x4*>(bf2 + nc);
#pragma unroll
    for (int rg = 0; rg < 2; ++rg) {
      float sum = 0.f, sq = 0.f;
#pragma unroll
      for (int r = 0; r < 4; ++r) {
        float v = acc3[rg][r] + bi[r] + xv[rg][r];
        rv2[rg][r] = v;
        sum += v; sq += v * v;
      }
      sum += __shfl_xor(sum, 16); sum += __shfl_xor(sum, 32);
      sq  += __shfl_xor(sq, 16);  sq  += __shfl_xor(sq, 32);
      stats[rg][wn][ln][0] = sum;
      stats[rg][wn][ln][1] = sq;
    }
  }
  __syncthreads();
  {
    f32x4 ga, bb;
    if (wn < 2) { ga = *reinterpret_cast<const f32x4*>(g2t + nc);
                  bb = *reinterpret_cast<const f32x4*>(b2t + nc); }
    else        { ga = *reinterpret_cast<const f32x4*>(g2s + nc - 32);
                  bb = *reinterpret_cast<const f32x4*>(b2s + nc - 32); }
#pragma unroll
    for (int rg = 0; rg < 2; ++rg) {
      float mu, rs;
      if (wn < 2) {
        float s  = stats[rg][0][ln][0] + stats[rg][1][ln][0];
        float q2 = stats[rg][0][ln][1] + stats[rg][1][ln][1];
        mu = s * (1.f / 32.f);
        rs = rsqrtf(q2 * (1.f / 32.f) - mu * mu + EPSV);
      } else {
        float s  = stats[rg][2][ln][0] + stats[rg][3][ln][0] + stats[rg][4][ln][0]
                 + stats[rg][5][ln][0] + stats[rg][6][ln][0] + stats[rg][7][ln][0];
        float q2 = stats[rg][2][ln][1] + stats[rg][3][ln][1] + stats[rg][4][ln][1]
                 + stats[rg][5][ln][1] + stats[rg][6][ln][1] + stats[rg][7][ln][1];
        mu = s * (1.f / 96.f);
        rs = rsqrtf(q2 * (1.f / 96.f) - mu * mu + EPSV);
      }
      int row = blockIdx.x * 32 + rg * 16 + ln;
      f32x4 o4;
#pragma unroll
      for (int r = 0; r < 4; ++r)
        o4[r] = (rv2[rg][r] - mu) * rs * ga[r] + bb[r];
      *reinterpret_cast<f32x4*>(out + (size_t)row * D + nc) = o4;
    }
  }
}

extern "C" void kernel_launch(void* const* d_in, const int* in_sizes, int n_in,
                              void* d_out, int out_size, void* d_ws, size_t ws_size,
                              hipStream_t stream) {
  (void)in_sizes; (void)n_in; (void)out_size; (void)ws_size;
  const float* x   = (const float*)d_in[0];
  const float* Wq  = (const float*)d_in[1];
  const float* bq  = (const float*)d_in[2];
  const float* Wk  = (const float*)d_in[3];
  const float* bk  = (const float*)d_in[4];
  const float* Wv  = (const float*)d_in[5];
  const float* bv  = (const float*)d_in[6];
  const float* Wo  = (const float*)d_in[7];
  const float* bo  = (const float*)d_in[8];
  const float* g1t = (const float*)d_in[9];
  const float* b1t = (const float*)d_in[10];
  const float* g1s = (const float*)d_in[11];
  const float* b1s = (const float*)d_in[12];
  const float* W1  = (const float*)d_in[13];
  const float* bf1 = (const float*)d_in[14];
  const float* W2  = (const float*)d_in[15];
  const float* bf2 = (const float*)d_in[16];
  const float* g2t = (const float*)d_in[17];
  const float* b2t = (const float*)d_in[18];
  const float* g2s = (const float*)d_in[19];
  const float* b2s = (const float*)d_in[20];

  char* ws = (char*)d_ws;
  unsigned short* xb  = (unsigned short*)(ws);                 // frag-linear x
  unsigned short* wqT = (unsigned short*)(ws + 4194304);
  unsigned short* wkT = wqT + 16384;
  unsigned short* wvT = wkT + 16384;
  unsigned short* woT = wvT + 16384;
  unsigned short* w1T = woT + 16384;   // frag-linear [32 tiles][4][64][8]
  unsigned short* w2T = w1T + 65536;   // frag-linear [8 tiles][16][64][8]
  unsigned short* qb  = w2T + 65536;   // fragment-linear Q
  unsigned short* kb  = qb + 2097152;  // fragment-linear K
  unsigned short* vT  = kb + 2097152;  // fragment-linear V
  unsigned short* ao  = vT + 2097152;  // fragment-linear attn output
  float* outp = (float*)d_out;

  prep_kernel<<<1792, 256, 0, stream>>>(x, Wq, Wk, Wv, Wo, W1, W2,
                                        xb, wqT, wkT, wvT, woT, w1T, w2T);
  qkv_kernel<<<dim3(256, 3), 256, 0, stream>>>(xb, wqT, wkT, wvT, bq, bk, bv, qb, kb, vT);
  attn_kernel<<<1024, 512, 0, stream>>>(qb, kb, vT, ao);
  tail_kernel<<<512, 512, 0, stream>>>(ao, woT, bo, x, g1t, b1t, g1s, b1s,
                                       w1T, bf1, w2T, bf2, g2t, b2t, g2s, b2s, outp);
}